// Round 4
// baseline (97.340 us; speedup 1.0000x reference)
//
#include <hip/hip_runtime.h>
#include <hip/hip_bf16.h>

// VQ-VAE vector quantizer, MI355X gfx950.
// z: [16,64,64,64] fp32, embed: [1024,64] fp32.
// out: z_q_st [16,64,64,64] fp32, then loss scalar.
//
// R1: bf16-MFMA distances + fused argmin. 46 us main; 1 block/CU -> latency.
// R2: 1024 blocks, 4-wave K-split, no z LDS tile. total 101 us.
// R3: packed (dist|code) u32 argmin (v_min_u32 everywhere). total 97.2 us.
// R4: A-frags via cooperative LDS staging (was: 64 semi-coalesced global
//     loads/lane, duplicated by all 4 waves). 8 KB bf16 tile, XOR-swizzled
//     chunk layout -> ds_read_b128/ds_write_b128 at the optimal 8 phases.
//     Per-thread: VMEM 64->16 (+2 ds_write, +8 ds_read), cvt 32->8.

#define K_CODES   1024
#define C_DIM     64
#define HW        4096
#define CHW       262144
#define OUT_ELEMS 4194304
#define LOSS_SCALE (1.25f / 4194304.0f)
#define KEY_MASK  0xFFFFFC00u   // keep sign+exp+top13 mantissa; low 10 bits = code

typedef short v8s __attribute__((ext_vector_type(8)));
typedef float v4f __attribute__((ext_vector_type(4)));

__device__ __forceinline__ unsigned short f2bf(float x) {
  unsigned int u = __float_as_uint(x);
  return (unsigned short)((u + 0x7FFFu + ((u >> 16) & 1u)) >> 16);
}

__device__ __forceinline__ ushort2 f2bf2(float x, float y) {
  union { __hip_bfloat162 h; ushort2 u; } c;
  c.h = __float22bfloat162_rn(make_float2(x, y));
  return c.u;
}

// ---------------------------------------------------------------------------
// Setup kernel: 32 blocks x 256 threads.
//  - packs embed into bf16 B-fragment order (tile t, k-half h, lane l):
//    ws_frag[t*128 + h*64 + l] = embed[t*16+(l&15)][h*32+(l>>4)*8 ..+7] as bf16
//  - ws_norm[k] = ||embed[k]||^2 + 1.0 (key bias), fp32
//  - thread 0 zeroes the loss accumulator.
// ---------------------------------------------------------------------------
__global__ __launch_bounds__(256) void vq_setup(const float* __restrict__ embed,
                                                float* __restrict__ ws_norm,
                                                uint4* __restrict__ ws_frag,
                                                float* __restrict__ out_loss) {
  int id = blockIdx.x * 256 + threadIdx.x;   // 0..8191
  int t   = id >> 7;
  int r   = id & 127;
  int h   = r >> 6;
  int l   = r & 63;
  int col = l & 15;
  int q   = l >> 4;
  int code = t * 16 + col;
  const float* src = embed + code * C_DIM + h * 32 + q * 8;
  float4 f0 = ((const float4*)src)[0];
  float4 f1 = ((const float4*)src)[1];
  union { unsigned short u[8]; uint4 q4; } pk;
  pk.u[0] = f2bf(f0.x); pk.u[1] = f2bf(f0.y); pk.u[2] = f2bf(f0.z); pk.u[3] = f2bf(f0.w);
  pk.u[4] = f2bf(f1.x); pk.u[5] = f2bf(f1.y); pk.u[6] = f2bf(f1.z); pk.u[7] = f2bf(f1.w);
  ws_frag[id] = pk.q4;

  if (id < K_CODES) {
    const float4* row = (const float4*)(embed + id * C_DIM);
    float s = 0.f;
#pragma unroll
    for (int i = 0; i < 16; ++i) {
      float4 v = row[i];
      s += v.x * v.x + v.y * v.y + v.z * v.z + v.w * v.w;
    }
    ws_norm[id] = s + 1.0f;   // keys = dist+1 > 0 (bits order-monotone)
  }
  if (id == 0) *out_loss = 0.f;
}

// ---------------------------------------------------------------------------
// Main kernel: 1024 blocks x 256 threads (4 waves).
// Block = 64 positions: b = blk>>6, h = blk&63, w = 0..63.
// Stage z tile once as bf16 in LDS (XOR-swizzled 16B chunks), then each wave
// computes packed-key argmin over its 256-code slice; waves merge via u32 min.
// ---------------------------------------------------------------------------
__global__ __launch_bounds__(256, 4) void vq_main(const float* __restrict__ z,
                                                  const float* __restrict__ embed,
                                                  const float* __restrict__ ws_norm,
                                                  const uint4* __restrict__ ws_frag,
                                                  float* __restrict__ out) {
  // zb16[pos][chunk]: chunk = 8 channels (16 B), stored at chunk^(pos&7).
  __shared__ unsigned short zb16[64 * 64];   // 8 KB
  __shared__ unsigned int rmin[4][64];
  __shared__ int idx_lds[64];
  __shared__ float wl[4];

  const int tid  = threadIdx.x;
  const int lane = tid & 63;
  const int wave = tid >> 6;
  const int col  = lane & 15;
  const int q    = lane >> 4;
  const int b    = blockIdx.x >> 6;
  const int h    = blockIdx.x & 63;
  const float* zb = z + b * CHW + h * 64;   // + c*HW + w

  // ---- cooperative stage: z (fp32, coalesced over w) -> bf16 LDS tile ----
  {
    const int w  = tid & 63;
    const int cg = tid >> 6;          // chunk group 0..3
#pragma unroll
    for (int s = 0; s < 2; ++s) {
      const int chunk = cg + s * 4;   // 0..7
      const float* src = zb + (chunk * 8) * HW + w;
      float f[8];
#pragma unroll
      for (int j = 0; j < 8; ++j) f[j] = src[j * HW];
      union { uint4 q4; ushort2 u2[4]; } pk;
#pragma unroll
      for (int j = 0; j < 4; ++j) pk.u2[j] = f2bf2(f[2 * j], f[2 * j + 1]);
      const int sw = chunk ^ (w & 7);
      *(uint4*)&zb16[w * 64 + sw * 8] = pk.q4;
    }
  }
  __syncthreads();

  // ---- A-frags from LDS: 8 x ds_read_b128 per lane ----
  // A layout: lane m=lane&15 holds A[m][q*8+j]; hf selects k-half (c += 32).
  v8s afrag[4][2];
#pragma unroll
  for (int g = 0; g < 4; ++g) {
    const int pos = g * 16 + col;
#pragma unroll
    for (int hf = 0; hf < 2; ++hf) {
      const int chunk = hf * 4 + q;
      const int sw = chunk ^ (pos & 7);
      afrag[g][hf] = *(const v8s*)&zb16[pos * 64 + sw * 8];
    }
  }

  unsigned int umin[4][4];
#pragma unroll
  for (int g = 0; g < 4; ++g)
#pragma unroll
    for (int r = 0; r < 4; ++r) umin[g][r] = 0xFFFFFFFFu;

  // ---- K loop: this wave's 16 code-tiles (256 codes) ----
  // D layout (verified m89/m91): col = lane&15 (code), row = q*4+reg (position).
  const int t0 = wave * 16;
#pragma unroll 4
  for (int tt = 0; tt < 16; ++tt) {
    const int t = t0 + tt;
    uint4 bu0 = ws_frag[t * 128 + lane];        // k  0..31
    uint4 bu1 = ws_frag[t * 128 + 64 + lane];   // k 32..63
    float nrm1 = ws_norm[t * 16 + col];         // ||e||^2 + 1
    union { uint4 q4; v8s v; } bb0, bb1;
    bb0.q4 = bu0; bb1.q4 = bu1;
    unsigned int code = (unsigned int)(t * 16 + col);
#pragma unroll
    for (int g = 0; g < 4; ++g) {
      v4f acc = {0.f, 0.f, 0.f, 0.f};
      acc = __builtin_amdgcn_mfma_f32_16x16x32_bf16(afrag[g][0], bb0.v, acc, 0, 0, 0);
      acc = __builtin_amdgcn_mfma_f32_16x16x32_bf16(afrag[g][1], bb1.v, acc, 0, 0, 0);
#pragma unroll
      for (int r = 0; r < 4; ++r) {
        float key = fmaf(-2.f, acc[r], nrm1);                       // dist+1 > 0
        unsigned int u = (__float_as_uint(key) & KEY_MASK) | code;  // v_and_or_b32
        umin[g][r] = min(umin[g][r], u);                            // v_min_u32
      }
    }
  }

  // ---- reduce across the 16 cols: pure u32 min (tie -> lower code) ----
#pragma unroll
  for (int off = 1; off < 16; off <<= 1) {
#pragma unroll
    for (int g = 0; g < 4; ++g)
#pragma unroll
      for (int r = 0; r < 4; ++r) {
        unsigned int ov = (unsigned int)__shfl_xor((int)umin[g][r], off, 64);
        umin[g][r] = min(umin[g][r], ov);
      }
  }
  if (col == 0) {
#pragma unroll
    for (int g = 0; g < 4; ++g)
#pragma unroll
      for (int r = 0; r < 4; ++r)
        rmin[wave][g * 16 + q * 4 + r] = umin[g][r];
  }
  __syncthreads();

  // ---- merge across waves (codes ascend with wave; u32 min keeps lowest) ----
  if (tid < 64) {
    unsigned int bv = min(min(rmin[0][tid], rmin[1][tid]),
                          min(rmin[2][tid], rmin[3][tid]));
    idx_lds[tid] = (int)(bv & 1023u);
  }
  __syncthreads();

  // ---- epilogue: z_q scatter (exact fp32 embed) + loss (z re-read, L3-hot) ----
  float lacc = 0.f;
  {
    const int w  = tid & 63;
    const int cq = tid >> 6;     // 0..3 -> 16 channels each
    const int idx = idx_lds[w];
    const float4* erow = (const float4*)(embed + idx * C_DIM);
    float* ob = out + b * CHW + h * 64 + w;
    const float* zp = zb + w;
#pragma unroll
    for (int j = 0; j < 4; ++j) {
      int c = cq * 16 + j * 4;
      float4 ev = erow[c >> 2];
      ob[(c + 0) * HW] = ev.x;
      ob[(c + 1) * HW] = ev.y;
      ob[(c + 2) * HW] = ev.z;
      ob[(c + 3) * HW] = ev.w;
      float dx = ev.x - zp[(c + 0) * HW];
      float dy = ev.y - zp[(c + 1) * HW];
      float dz = ev.z - zp[(c + 2) * HW];
      float dw = ev.w - zp[(c + 3) * HW];
      lacc += dx * dx + dy * dy + dz * dz + dw * dw;
    }
  }
#pragma unroll
  for (int off = 32; off >= 1; off >>= 1) lacc += __shfl_xor(lacc, off, 64);
  if (lane == 0) wl[wave] = lacc;
  __syncthreads();
  if (tid == 0) {
    float s = (wl[0] + wl[1]) + (wl[2] + wl[3]);
    atomicAdd(out + OUT_ELEMS, s * LOSS_SCALE);  // zeroed by vq_setup, same stream
  }
}

extern "C" void kernel_launch(void* const* d_in, const int* in_sizes, int n_in,
                              void* d_out, int out_size, void* d_ws, size_t ws_size,
                              hipStream_t stream) {
  const float* z     = (const float*)d_in[0];
  const float* embed = (const float*)d_in[1];
  float* out = (float*)d_out;
  // d_ws layout: [0,4096) biased norms fp32 (1024 used), [4096, +131072) bf16 frags
  float* ws_norm = (float*)d_ws;
  uint4* ws_frag = (uint4*)((char*)d_ws + 4096);

  vq_setup<<<32, 256, 0, stream>>>(embed, ws_norm, ws_frag, out + OUT_ELEMS);
  vq_main<<<1024, 256, 0, stream>>>(z, embed, ws_norm, (const uint4*)ws_frag, out);
}